// Round 10
// baseline (121.515 us; speedup 1.0000x reference)
//
#include <hip/hip_runtime.h>
#include <math.h>

#define NQ 12
#define DIM 4096
#define BATCH 2048

// Native clang vector type: __builtin_nontemporal_* requires a true vector of
// scalars, not HIP's HIP_vector_type<float,4> class.
typedef float fv4 __attribute__((ext_vector_type(4)));

#if defined(__has_builtin)
#if __has_builtin(__builtin_nontemporal_load) && __has_builtin(__builtin_nontemporal_store)
#define NT_LOAD(p)     __builtin_nontemporal_load(p)
#define NT_STORE(p, v) __builtin_nontemporal_store((v), (p))
#endif
#endif
#ifndef NT_LOAD
#define NT_LOAD(p)     (*(p))
#define NT_STORE(p, v) (*(p) = (v))
#endif

// XOR swizzle on float2 index: every LDS access pattern below lands at the
// b64 minimum (4 lanes per bank-pair). Bijective on [0,4096).
__device__ __forceinline__ int swz(int e) { return e ^ ((e >> 4) & 15); }

__device__ __forceinline__ float2 cmul(float2 a, float2 b) {
    return make_float2(a.x * b.x - a.y * b.y, a.x * b.y + a.y * b.x);
}

// Unscaled B-butterfly over all 4 local bits: for pair (u=bit0, w=bit1):
//   u' = u + i*w ; w' = w + i*u     (1/sqrt2 scaling folded into hi_th/hi_ph)
__device__ __forceinline__ void bf4(float (&vr)[16], float (&vi)[16]) {
#pragma unroll
    for (int m = 1; m < 16; m <<= 1) {
#pragma unroll
        for (int r = 0; r < 16; ++r) {
            if (r & m) continue;
            const int p = r | m;
            float ur = vr[r], ui = vi[r], wr = vr[p], wi = vi[p];
            vr[r] = ur - wi;  vi[r] = ui + wr;
            vr[p] = wr - ui;  vi[p] = wi + ur;
        }
    }
}

// Layouts (elem index bits; t = thread 0..255, r = local 0..15):
//  A: elem = r[3:2]<<10 | t<<2 | r[1:0]      local bits {0,1,10,11} (coalesced I/O)
//  B: elem = t[7:2]<<6  | r<<2 | t[1:0]      local bits {2,3,4,5}
//  C: elem = t[7:6]<<10 | r<<6 | t[5:0]      local bits {6,7,8,9}
//
// Diagonal phases factor: phase(e) = phase_hi(e>>6) + phase_lo(e&63)
// (qubit k <-> elem bit 11-k; k=0..5 -> hi bits, k=6..11 -> lo bits), so each
// block builds six 64-entry cis-tables in LDS (no global workspace needed).
//
// INTERLEAVED=1: store complex64 (re,im) pairs (out has 2*BATCH*DIM floats).
// INTERLEAVED=0: store real part only   (out has   BATCH*DIM floats) —
//   matches a harness that casts the complex64 reference to float32.
template <bool INTERLEAVED>
__global__ __launch_bounds__(256, 4) void qlayer(
        const float* __restrict__ xr, const float* __restrict__ xi,
        const float* __restrict__ alphas, const float* __restrict__ betas,
        const float* __restrict__ thetas, const float* __restrict__ phis,
        float* __restrict__ out) {
    __shared__ float2 lds[DIM];
    __shared__ float2 hi_in[64], lo_in[64];
    __shared__ float2 hi_th[64], lo_th[64];
    __shared__ float2 hi_ph[64], lo_ph[64];

    const int row = blockIdx.x;
    const int t = threadIdx.x;

    const float* xrp = xr + (size_t)row * DIM;
    const float* xip = xi + (size_t)row * DIM;

    // ---- issue x loads early (layout A, float4-coalesced, non-temporal) ----
    fv4 re[4], im[4];
#pragma unroll
    for (int c = 0; c < 4; ++c) {
        const int e0 = (c << 10) + (t << 2);
        re[c] = NT_LOAD(reinterpret_cast<const fv4*>(xrp + e0));
        im[c] = NT_LOAD(reinterpret_cast<const fv4*>(xip + e0));
    }

    // ---- build per-block phase factor tables (overlaps with x loads) ----
    // hi index h: bit (5-k) of h is qubit k (k=0..5).
    // lo index l: bit (11-k) of l is qubit k (k=6..11).
    if (t < 64) {
        float p_in = 0.f, p_th = 0.f, p_ph = 0.f;
#pragma unroll
        for (int k = 0; k < 6; ++k) {
            if ((t >> (5 - k)) & 1) {
                p_in += betas[k];
            } else {
                p_in += alphas[k]; p_th += thetas[k]; p_ph += phis[k];
            }
        }
        const float g = 1.0f / 64.0f;   // 12 stages of 1/sqrt2 per pass
        float s, c;
        sincosf(p_in, &s, &c); hi_in[t] = make_float2(c, s);
        sincosf(p_th, &s, &c); hi_th[t] = make_float2(c * g, s * g);
        sincosf(p_ph, &s, &c); hi_ph[t] = make_float2(c * g, s * g);
    } else if (t < 128) {
        const int l = t - 64;
        float p_in = 0.f, p_th = 0.f, p_ph = 0.f;
#pragma unroll
        for (int k = 6; k < 12; ++k) {
            if ((l >> (11 - k)) & 1) {
                p_in += betas[k];
            } else {
                p_in += alphas[k]; p_th += thetas[k]; p_ph += phis[k];
            }
        }
        float s, c;
        sincosf(p_in, &s, &c); lo_in[l] = make_float2(c, s);
        sincosf(p_th, &s, &c); lo_th[l] = make_float2(c, s);
        sincosf(p_ph, &s, &c); lo_ph[l] = make_float2(c, s);
    }
    __syncthreads();

    float vr[16], vi[16];

    // ---- d_in multiply (layout A: e = c<<10 | t<<2 | j) ----
    // lo index = ((t&15)<<2)|j (independent of c); hi index = (c<<4)|(t>>4).
    float2 fin[4];
#pragma unroll
    for (int j = 0; j < 4; ++j) fin[j] = lo_in[((t & 15) << 2) | j];
#pragma unroll
    for (int c = 0; c < 4; ++c) {
        const float2 fhi = hi_in[(c << 4) | (t >> 4)];
#pragma unroll
        for (int j = 0; j < 4; ++j) {
            const float2 d = cmul(fhi, fin[j]);
            const float rr = re[c][j], ii = im[c][j];
            vr[c * 4 + j] = rr * d.x - ii * d.y;
            vi[c * 4 + j] = rr * d.y + ii * d.x;
        }
    }

    bf4(vr, vi);                       // bits {0,1,10,11}

    // ---- swap A -> B ----
#pragma unroll
    for (int r = 0; r < 16; ++r) {
        const int e = ((r >> 2) << 10) | (t << 2) | (r & 3);
        lds[swz(e)] = make_float2(vr[r], vi[r]);
    }
    __syncthreads();
#pragma unroll
    for (int r = 0; r < 16; ++r) {
        const int e = ((t >> 2) << 6) | (r << 2) | (t & 3);
        float2 v = lds[swz(e)];
        vr[r] = v.x; vi[r] = v.y;
    }
    __syncthreads();

    bf4(vr, vi);                       // bits {2,3,4,5}

    // ---- swap B -> C ----
#pragma unroll
    for (int r = 0; r < 16; ++r) {
        const int e = ((t >> 2) << 6) | (r << 2) | (t & 3);
        lds[swz(e)] = make_float2(vr[r], vi[r]);
    }
    __syncthreads();
#pragma unroll
    for (int r = 0; r < 16; ++r) {
        const int e = ((t >> 6) << 10) | (r << 6) | (t & 63);
        float2 v = lds[swz(e)];
        vr[r] = v.x; vi[r] = v.y;
    }
    __syncthreads();

    bf4(vr, vi);                       // bits {6,7,8,9} — first pass done

    // ---- d_th multiply (layout C: e = (t>>6)<<10 | r<<6 | (t&63)) ----
    {
        const float2 flo = lo_th[t & 63];
#pragma unroll
        for (int r = 0; r < 16; ++r) {
            const float2 d = cmul(hi_th[((t >> 6) << 4) | r], flo);
            const float a = vr[r], b = vi[r];
            vr[r] = a * d.x - b * d.y;
            vi[r] = a * d.y + b * d.x;
        }
    }

    bf4(vr, vi);                       // bits {6,7,8,9}

    // ---- swap C -> B ----
#pragma unroll
    for (int r = 0; r < 16; ++r) {
        const int e = ((t >> 6) << 10) | (r << 6) | (t & 63);
        lds[swz(e)] = make_float2(vr[r], vi[r]);
    }
    __syncthreads();
#pragma unroll
    for (int r = 0; r < 16; ++r) {
        const int e = ((t >> 2) << 6) | (r << 2) | (t & 3);
        float2 v = lds[swz(e)];
        vr[r] = v.x; vi[r] = v.y;
    }
    __syncthreads();

    bf4(vr, vi);                       // bits {2,3,4,5}

    // ---- swap B -> A ----
#pragma unroll
    for (int r = 0; r < 16; ++r) {
        const int e = ((t >> 2) << 6) | (r << 2) | (t & 3);
        lds[swz(e)] = make_float2(vr[r], vi[r]);
    }
    __syncthreads();
#pragma unroll
    for (int r = 0; r < 16; ++r) {
        const int e = ((r >> 2) << 10) | (t << 2) | (r & 3);
        float2 v = lds[swz(e)];
        vr[r] = v.x; vi[r] = v.y;
    }
    // no more LDS writes -> no trailing barrier

    bf4(vr, vi);                       // bits {0,1,10,11}

    // ---- d_ph multiply + store (layout A) ----
    float2 fph[4];
#pragma unroll
    for (int j = 0; j < 4; ++j) fph[j] = lo_ph[((t & 15) << 2) | j];

    if (INTERLEAVED) {
        float* outp = out + (size_t)row * DIM * 2;
#pragma unroll
        for (int c = 0; c < 4; ++c) {
            const int e0 = (c << 10) + (t << 2);
            const float2 fhi = hi_ph[(c << 4) | (t >> 4)];
            fv4 o0, o1;
#pragma unroll
            for (int j = 0; j < 4; ++j) {
                const float2 d = cmul(fhi, fph[j]);
                const float a = vr[c * 4 + j], b = vi[c * 4 + j];
                const float orr = a * d.x - b * d.y;
                const float oii = a * d.y + b * d.x;
                if (j < 2) { o0[2 * j] = orr; o0[2 * j + 1] = oii; }
                else       { o1[2 * (j - 2)] = orr; o1[2 * (j - 2) + 1] = oii; }
            }
            NT_STORE(reinterpret_cast<fv4*>(outp + 2 * e0), o0);
            NT_STORE(reinterpret_cast<fv4*>(outp + 2 * e0 + 4), o1);
        }
    } else {
        // Real part only: out is [BATCH][DIM] float32.
        float* outp = out + (size_t)row * DIM;
#pragma unroll
        for (int c = 0; c < 4; ++c) {
            const int e0 = (c << 10) + (t << 2);
            const float2 fhi = hi_ph[(c << 4) | (t >> 4)];
            fv4 o;
#pragma unroll
            for (int j = 0; j < 4; ++j) {
                const float2 d = cmul(fhi, fph[j]);
                o[j] = vr[c * 4 + j] * d.x - vi[c * 4 + j] * d.y;
            }
            NT_STORE(reinterpret_cast<fv4*>(outp + e0), o);
        }
    }
}

extern "C" void kernel_launch(void* const* d_in, const int* in_sizes, int n_in,
                              void* d_out, int out_size, void* d_ws, size_t ws_size,
                              hipStream_t stream) {
    const float* xr     = (const float*)d_in[0];
    const float* xi     = (const float*)d_in[1];
    const float* alphas = (const float*)d_in[2];
    const float* betas  = (const float*)d_in[3];
    const float* thetas = (const float*)d_in[4];
    const float* phis   = (const float*)d_in[5];

    // out_size-adaptive store: complex64 interleaved needs 2*BATCH*DIM floats;
    // a float32-cast (real part) reference needs BATCH*DIM. Never write more
    // than out_size floats (Round 7 core dump = 64 MiB store into 32 MiB buf).
    if (out_size >= 2 * BATCH * DIM) {
        qlayer<true><<<BATCH, 256, 0, stream>>>(xr, xi, alphas, betas, thetas,
                                                phis, (float*)d_out);
    } else {
        qlayer<false><<<BATCH, 256, 0, stream>>>(xr, xi, alphas, betas, thetas,
                                                 phis, (float*)d_out);
    }
}